// Round 1
// baseline (16.036 us; speedup 1.0000x reference)
//
#include <hip/hip_runtime.h>

#define QN 64
#define PATCH 32
#define HH 512
#define WW 512
#define NPIX (4 * 512 * 512)

__global__ __launch_bounds__(256) void render_kernel(
    const float* __restrict__ patch,    // [B,Q,32,32]
    const float* __restrict__ centers,  // [B,Q,2]
    const float* __restrict__ depth,    // [B,Q,1]
    const float* __restrict__ sizes,    // [B,Q,2]
    const float* __restrict__ dscale,   // [B,Q,1]
    float* __restrict__ out)            // [identity | depth | occ], each B*H*W
{
#pragma clang fp contract(off)
    const int tid = threadIdx.x;
    const int b   = blockIdx.z;
    const int x   = (blockIdx.x << 4) + (tid & 15);
    const int y   = (blockIdx.y << 4) + (tid >> 4);

    __shared__ float sp[QN][8];   // sorted params: cx, cy, sx, sy, depth, ident, orig_q
    __shared__ float sdep[QN];
    __shared__ int   slist[QN];
    __shared__ int   scount;
    __shared__ float smean;

    // ---- stage depths ----
    if (tid < QN) sdep[tid] = depth[(b << 6) + tid];
    __syncthreads();

    // ---- per-batch stable descending-depth rank sort + mean(depth_scale) ----
    if (tid < QN) {
        const float d = sdep[tid];
        int rank = 0;
#pragma unroll
        for (int j = 0; j < QN; ++j) {
            const float dj = sdep[j];
            rank += ((dj > d) || ((dj == d) && (j < tid))) ? 1 : 0;
        }
        const int gi = (b << 6) + tid;
        sp[rank][0] = centers[gi * 2 + 0];
        sp[rank][1] = centers[gi * 2 + 1];
        sp[rank][2] = sizes[gi * 2 + 0];
        sp[rank][3] = sizes[gi * 2 + 1];
        sp[rank][4] = d;
        sp[rank][5] = (float)(tid + 1);        // ident value = orig index + 1
        sp[rank][6] = __int_as_float(tid);     // orig index (patch lookup)

        float v = dscale[gi];
        for (int off = 32; off; off >>= 1) v += __shfl_down(v, off);
        if (tid == 0) smean = v * (1.0f / 64.0f);
    }
    __syncthreads();

    const float STEP = 2.0f / 511.0f;

    // ---- conservative tile-vs-query bbox cull (order-preserving compaction) ----
    if (tid < QN) {
        const float gx_lo = -1.0f + (float)(blockIdx.x << 4) * STEP;
        const float gx_hi = -1.0f + (float)((blockIdx.x << 4) + 15) * STEP;
        const float gy_lo = -1.0f + (float)(blockIdx.y << 4) * STEP;
        const float gy_hi = -1.0f + (float)((blockIdx.y << 4) + 15) * STEP;
        // sample is exactly 0 when |lx| >= 1 + 1/15.5 = 1.064516...; 1.066 is conservative
        const float C = 1.0660f;
        const float cx = sp[tid][0], cy = sp[tid][1];
        const float sxv = sp[tid][2], syv = sp[tid][3];
        const bool keep = (cx + C * sxv >= gx_lo) && (cx - C * sxv <= gx_hi) &&
                          (cy + C * syv >= gy_lo) && (cy - C * syv <= gy_hi);
        const unsigned long long m = __ballot(keep);
        if (keep) slist[__popcll(m & ((1ull << tid) - 1ull))] = tid;
        if (tid == 0) scount = (int)__popcll(m);
    }
    __syncthreads();

    // ---- per-pixel composite over surviving queries (front-to-back) ----
    const float gx = -1.0f + (float)x * STEP;
    const float gy = -1.0f + (float)y * STEP;

    float t = 1.0f;
    float dep = 0.0f;
    float identv = 0.0f;
    bool  anyhit = false;
    const int cnt = scount;

    for (int i = 0; i < cnt; ++i) {
        const int q = slist[i];
        const float cx = sp[q][0], cy = sp[q][1];
        const float sxv = sp[q][2], syv = sp[q][3];
        const float dq = sp[q][4], iv = sp[q][5];
        const int pq = __float_as_int(sp[q][6]);

        float lx = (gx - cx) / sxv;
        lx = fminf(fmaxf(lx, -1.1f), 1.1f);
        float ly = (gy - cy) / syv;
        ly = fminf(fmaxf(ly, -1.1f), 1.1f);
        const float ix = (lx + 1.0f) * 0.5f * 31.0f;
        const float iy = (ly + 1.0f) * 0.5f * 31.0f;
        const float x0f = floorf(ix), y0f = floorf(iy);
        const float wx = ix - x0f, wy = iy - y0f;
        const int x0 = (int)x0f, y0 = (int)y0f;

        const float* pp = patch + (((size_t)(b << 6) + (size_t)pq) << 10);
        const bool xok0 = (x0 >= 0) && (x0 < PATCH);
        const bool xok1 = (x0 + 1 >= 0) && (x0 + 1 < PATCH);
        const bool yok0 = (y0 >= 0) && (y0 < PATCH);
        const bool yok1 = (y0 + 1 >= 0) && (y0 + 1 < PATCH);
        const float v00 = (xok0 && yok0) ? pp[(y0 << 5) + x0] : 0.0f;
        const float v01 = (xok1 && yok0) ? pp[(y0 << 5) + x0 + 1] : 0.0f;
        const float v10 = (xok0 && yok1) ? pp[((y0 + 1) << 5) + x0] : 0.0f;
        const float v11 = (xok1 && yok1) ? pp[((y0 + 1) << 5) + x0 + 1] : 0.0f;

        const float a = v00 * (1.0f - wx) * (1.0f - wy)
                      + v01 * wx * (1.0f - wy)
                      + v10 * (1.0f - wx) * wy
                      + v11 * wx * wy;

        const float contrib = a * t;
        if (!anyhit && (contrib > 0.001f)) { anyhit = true; identv = iv; }
        dep += contrib * dq;
        t *= (1.0f - a);
    }

    float occ = 1.0f - t;
    occ = fminf(fmaxf(occ, 0.0f), 1.0f);
    const float vis = (occ > 0.05f) ? 1.0f : 0.0f;
    float ido = anyhit ? identv : 0.0f;
    ido *= vis;
    const float dpo = (dep * vis) * smean;

    const size_t pix = (((size_t)b * HH) + (size_t)y) * WW + (size_t)x;
    out[pix] = ido;
    out[(size_t)NPIX + pix] = dpo;
    out[2 * (size_t)NPIX + pix] = occ;
}

extern "C" void kernel_launch(void* const* d_in, const int* in_sizes, int n_in,
                              void* d_out, int out_size, void* d_ws, size_t ws_size,
                              hipStream_t stream) {
    const float* patch   = (const float*)d_in[0];
    const float* centers = (const float*)d_in[1];
    const float* depth   = (const float*)d_in[2];
    const float* sizes   = (const float*)d_in[3];
    const float* dscale  = (const float*)d_in[4];
    float* out = (float*)d_out;

    dim3 grid(WW / 16, HH / 16, 4);
    render_kernel<<<grid, 256, 0, stream>>>(patch, centers, depth, sizes, dscale, out);
}

// Round 2
// 15.476 us; speedup vs baseline: 1.0362x; 1.0362x over previous
//
#include <hip/hip_runtime.h>

#define QN 64
#define PATCH 32
#define HH 512
#define WW 512
#define NPIX (4 * 512 * 512)

__global__ __launch_bounds__(256) void render_kernel(
    const float* __restrict__ patch,    // [B,Q,32,32]
    const float* __restrict__ centers,  // [B,Q,2]
    const float* __restrict__ depth,    // [B,Q,1]
    const float* __restrict__ sizes,    // [B,Q,2]
    const float* __restrict__ dscale,   // [B,Q,1]
    float* __restrict__ out)            // [identity | depth | occ], each B*H*W
{
#pragma clang fp contract(off)
    const int tid = threadIdx.x;
    const int b   = blockIdx.z;
    const int tx0 = blockIdx.x << 5;            // 32x32 pixel tile per block
    const int ty0 = blockIdx.y << 5;
    const int xp  = tx0 + ((tid & 7) << 2);     // 4 consecutive x per thread
    const int y   = ty0 + (tid >> 3);

    __shared__ float sp[QN][8];   // rank-sorted: cx, cy, sx, sy, depth, ident, orig_q
    __shared__ int   slist[QN];
    __shared__ int   scount;
    __shared__ float smean;

    const float STEP = 2.0f / 511.0f;

    // ---- wave 0 does everything serial: sort, mean, cull, compact (no barrier needed
    //      between its own LDS write and read; lgkmcnt handles intra-wave RAW) ----
    if (tid < QN) {
        const int gi = (b << 6) + tid;
        const float d   = depth[gi];
        const float cx0 = centers[gi * 2 + 0];
        const float cy0 = centers[gi * 2 + 1];
        const float sx0 = sizes[gi * 2 + 0];
        const float sy0 = sizes[gi * 2 + 1];

        // stable descending-depth rank via shuffles (no LDS, no barrier)
        int rank = 0;
#pragma unroll
        for (int j = 0; j < QN; ++j) {
            const float dj = __shfl(d, j);
            rank += ((dj > d) || ((dj == d) && (j < tid))) ? 1 : 0;
        }
        sp[rank][0] = cx0;
        sp[rank][1] = cy0;
        sp[rank][2] = sx0;
        sp[rank][3] = sy0;
        sp[rank][4] = d;
        sp[rank][5] = (float)(tid + 1);        // ident value = orig index + 1
        sp[rank][6] = __int_as_float(tid);     // orig index (patch lookup)

        float v = dscale[gi];
        for (int off = 32; off; off >>= 1) v += __shfl_down(v, off);
        if (tid == 0) smean = v * (1.0f / 64.0f);

        // conservative tile-vs-query bbox cull, rank order preserved.
        // sample is exactly 0 when |lx| >= 1 + 1/15.5 = 1.064516..; 1.0660 conservative.
        const float gx_lo = -1.0f + (float)tx0 * STEP;
        const float gx_hi = -1.0f + (float)(tx0 + 31) * STEP;
        const float gy_lo = -1.0f + (float)ty0 * STEP;
        const float gy_hi = -1.0f + (float)(ty0 + 31) * STEP;
        const float C = 1.0660f;
        const float cx = sp[tid][0], cy = sp[tid][1];
        const float sxv = sp[tid][2], syv = sp[tid][3];
        const bool keep = (cx + C * sxv >= gx_lo) && (cx - C * sxv <= gx_hi) &&
                          (cy + C * syv >= gy_lo) && (cy - C * syv <= gy_hi);
        const unsigned long long m = __ballot(keep);
        if (keep) slist[__popcll(m & ((1ull << tid) - 1ull))] = tid;  // tid = rank here
        if (tid == 0) scount = (int)__popcll(m);
    }
    __syncthreads();

    // ---- per-pixel composite over surviving queries, 4 px per thread ----
    const int cnt = scount;
    const float gy = -1.0f + (float)y * STEP;
    float gx[4];
#pragma unroll
    for (int k = 0; k < 4; ++k) gx[k] = -1.0f + (float)(xp + k) * STEP;

    float tr[4]  = {1.0f, 1.0f, 1.0f, 1.0f};
    float dp[4]  = {0.0f, 0.0f, 0.0f, 0.0f};
    float idv[4] = {0.0f, 0.0f, 0.0f, 0.0f};
    int hitm = 0;

    for (int i = 0; i < cnt; ++i) {
        const int q = slist[i];
        const float cx  = sp[q][0], cy  = sp[q][1];
        const float sxv = sp[q][2], syv = sp[q][3];
        const float dq  = sp[q][4], iv  = sp[q][5];
        const int   pq  = __float_as_int(sp[q][6]);
        const float* pp = patch + (((size_t)((b << 6) + pq)) << 10);

        // row math shared across the thread's 4 pixels (same y)
        float ly = (gy - cy) / syv;
        ly = fminf(fmaxf(ly, -1.1f), 1.1f);
        const float iy  = (ly + 1.0f) * 0.5f * 31.0f;
        const float y0f = floorf(iy);
        const float wy  = iy - y0f;
        const int   yi  = (int)y0f;
        const bool yok0 = (yi >= 0) && (yi < PATCH);
        const bool yok1 = (yi + 1 >= 0) && (yi + 1 < PATCH);
        const int row0 = yi << 5, row1 = (yi + 1) << 5;

#pragma unroll
        for (int k = 0; k < 4; ++k) {
            float lx = (gx[k] - cx) / sxv;
            lx = fminf(fmaxf(lx, -1.1f), 1.1f);
            const float ixf = (lx + 1.0f) * 0.5f * 31.0f;
            const float x0f = floorf(ixf);
            const float wx  = ixf - x0f;
            const int   xi  = (int)x0f;
            const bool xok0 = (xi >= 0) && (xi < PATCH);
            const bool xok1 = (xi + 1 >= 0) && (xi + 1 < PATCH);
            const float v00 = (xok0 && yok0) ? pp[row0 + xi] : 0.0f;
            const float v01 = (xok1 && yok0) ? pp[row0 + xi + 1] : 0.0f;
            const float v10 = (xok0 && yok1) ? pp[row1 + xi] : 0.0f;
            const float v11 = (xok1 && yok1) ? pp[row1 + xi + 1] : 0.0f;

            const float a = v00 * (1.0f - wx) * (1.0f - wy)
                          + v01 * wx * (1.0f - wy)
                          + v10 * (1.0f - wx) * wy
                          + v11 * wx * wy;

            const float contrib = a * tr[k];
            if (!(hitm & (1 << k)) && (contrib > 0.001f)) { hitm |= (1 << k); idv[k] = iv; }
            dp[k] += contrib * dq;
            tr[k] *= (1.0f - a);
        }
    }

    const float sm = smean;
    float4 o_id, o_dp, o_oc;
#pragma unroll
    for (int k = 0; k < 4; ++k) {
        float occ = 1.0f - tr[k];
        occ = fminf(fmaxf(occ, 0.0f), 1.0f);
        const float vis = (occ > 0.05f) ? 1.0f : 0.0f;
        ((float*)&o_id)[k] = idv[k] * vis;
        ((float*)&o_dp)[k] = (dp[k] * vis) * sm;
        ((float*)&o_oc)[k] = occ;
    }

    const size_t pix = ((size_t)b * HH + (size_t)y) * WW + (size_t)xp;
    *(float4*)(out + pix)                    = o_id;
    *(float4*)(out + (size_t)NPIX + pix)     = o_dp;
    *(float4*)(out + 2 * (size_t)NPIX + pix) = o_oc;
}

extern "C" void kernel_launch(void* const* d_in, const int* in_sizes, int n_in,
                              void* d_out, int out_size, void* d_ws, size_t ws_size,
                              hipStream_t stream) {
    const float* patch   = (const float*)d_in[0];
    const float* centers = (const float*)d_in[1];
    const float* depth   = (const float*)d_in[2];
    const float* sizes   = (const float*)d_in[3];
    const float* dscale  = (const float*)d_in[4];
    float* out = (float*)d_out;

    dim3 grid(WW / 32, HH / 32, 4);
    render_kernel<<<grid, 256, 0, stream>>>(patch, centers, depth, sizes, dscale, out);
}